// Round 12
// baseline (71.988 us; speedup 1.0000x reference)
//
#include <hip/hip_runtime.h>

using f16x8 = __attribute__((ext_vector_type(8))) _Float16;
using f16x4 = __attribute__((ext_vector_type(4))) _Float16;
using f32x4 = __attribute__((ext_vector_type(4))) float;

#define T_SEQ 2048
#define D_MODEL 512
#define NH 8
#define HD 64
#define NB 2
#define M_ROWS (NB * T_SEQ)   // 4096

// async global->LDS, 16B per lane. LDS dest must be wave-uniform base;
// HW adds lane*16. Source is per-lane.
#define GLOAD_LDS16(g, l)                                              \
  __builtin_amdgcn_global_load_lds(                                    \
      (const __attribute__((address_space(1))) void*)(g),              \
      (__attribute__((address_space(3))) void*)(l), 16, 0, 0)

// ================================================================ K1: qkv
// grid (4,32,3) = 384 blocks, all co-resident (48KB LDS -> 3 blocks/CU cap).
// ny==0 blocks (12) transpose-convert their (z,nx) weight panel f32->f16 wT
// and RELEASE-STORE flag[p] (12 plain stores -- no RMW contention). All
// blocks poll flag[p] with RELAXED loads (no per-poll cache maintenance --
// R9's acquire-poll storm) + ONE acquire at exit (R10-proven discipline).
// GEMM: A reg-staged from f32 x with in-flight f16 convert (no xh buffer,
// no cvt kernel); B via global_load_lds from wT. 3-buf counted pipeline.
__global__ __launch_bounds__(256) void k_qkvw(
    const float* __restrict__ x, const float* __restrict__ wq,
    const float* __restrict__ wk, const float* __restrict__ wv,
    const float* __restrict__ bq, const float* __restrict__ bk,
    const float* __restrict__ bv, _Float16* __restrict__ wT,
    _Float16* __restrict__ QKV, int* __restrict__ flags) {
  __shared__ __align__(16) char smraw[49152];
  const int nx = blockIdx.x, ny = blockIdx.y, z = blockIdx.z;
  const float* w = z == 0 ? wq : z == 1 ? wk : wv;
  const float* bias = z == 0 ? bq : z == 1 ? bk : bv;
  _Float16* wTz = wT + (size_t)z * D_MODEL * D_MODEL;
  const int p = z * 4 + nx;
  const int n0 = nx * 128, m0 = ny * 128;
  const int tid = threadIdx.x;

  if (ny == 0) {
    // transpose panel: w[k][n0..n0+128) f32 -> wTz[n][k] f16
    float* Lf = (float*)smraw;  // [64][136] padded
    for (int k0 = 0; k0 < D_MODEL; k0 += 64) {
      __syncthreads();
#pragma unroll
      for (int u = 0; u < 8; ++u) {
        int c = tid + u * 256;          // 2048 float4 chunks
        int row = c >> 5, ncl = (c & 31) * 4;
        *(float4*)&Lf[row * 136 + ncl] =
            *(const float4*)&w[(size_t)(k0 + row) * D_MODEL + n0 + ncl];
      }
      __syncthreads();
#pragma unroll
      for (int u = 0; u < 4; ++u) {
        int F = tid + u * 256;          // 1024 fragments (128n x 8kq)
        int n = F >> 3, kq = F & 7;
        f16x8 h;
#pragma unroll
        for (int j = 0; j < 8; ++j)
          h[j] = (_Float16)Lf[(kq * 8 + j) * 136 + n];
        *(f16x8*)&wTz[(size_t)(n0 + n) * D_MODEL + k0 + kq * 8] = h;
      }
    }
    __threadfence();
    __syncthreads();
    if (tid == 0)
      __hip_atomic_store(&flags[p], 1, __ATOMIC_RELEASE,
                         __HIP_MEMORY_SCOPE_AGENT);
  }
  // wait for panel: RELAXED poll (no cache ops), ONE acquire at exit
  if (tid == 0) {
    while (!__hip_atomic_load(&flags[p], __ATOMIC_RELAXED,
                              __HIP_MEMORY_SCOPE_AGENT))
      __builtin_amdgcn_s_sleep(8);
    (void)__hip_atomic_load(&flags[p], __ATOMIC_ACQUIRE,
                            __HIP_MEMORY_SCOPE_AGENT);
  }
  __syncthreads();

  // ---------------- GEMM ----------------
  constexpr int NT = D_MODEL / 32;  // 16
  _Float16* At = (_Float16*)smraw;              // 3 x 128x32
  _Float16* Bts = (_Float16*)(smraw + 24576);   // 3 x 128x32
  const int l = tid & 63;
  const int wvv = tid >> 6;
  const int wm = wvv >> 1, wn = wvv & 1;
  const int r16 = l & 15, g4 = l >> 4;
  f32x4 acc[4][4] = {};
  float4 ar[2][2];

  auto loadA = [&](int k0) {
#pragma unroll
    for (int cc = 0; cc < 2; ++cc) {
      int c = tid + cc * 256;
      int row = c >> 2, part = c & 3;
      const float* src = &x[(size_t)(m0 + row) * D_MODEL + k0 + part * 8];
      ar[cc][0] = *(const float4*)src;
      ar[cc][1] = *(const float4*)(src + 4);
    }
  };
  auto writeA = [&](int bb) {
#pragma unroll
    for (int cc = 0; cc < 2; ++cc) {
      int c = tid + cc * 256;
      int row = c >> 2, part = c & 3;
      f16x8 h;
#pragma unroll
      for (int j = 0; j < 4; ++j) {
        h[j] = (_Float16)ar[cc][0][j];
        h[4 + j] = (_Float16)ar[cc][1][j];
      }
      *(f16x8*)&At[bb * 4096 + row * 32 + ((part ^ (row & 3))) * 8] = h;
    }
  };
  auto stageB = [&](int bb, int k0) {
#pragma unroll
    for (int cc = 0; cc < 2; ++cc) {
      int c = tid + cc * 256;
      int row = c >> 2, sp = (c & 3) ^ (row & 3);
      GLOAD_LDS16(&wTz[(size_t)(n0 + row) * D_MODEL + k0 + sp * 8],
                  &Bts[bb * 4096 + (c - l) * 8]);
    }
  };
  auto compute = [&](int bb) {
    f16x8 a[4], b[4];
#pragma unroll
    for (int mf = 0; mf < 4; ++mf) {
      int row = wm * 64 + mf * 16 + r16;
      a[mf] = *(const f16x8*)&At[bb * 4096 + row * 32 + (g4 ^ (row & 3)) * 8];
    }
#pragma unroll
    for (int nf = 0; nf < 4; ++nf) {
      int row = wn * 64 + nf * 16 + r16;
      b[nf] = *(const f16x8*)&Bts[bb * 4096 + row * 32 + (g4 ^ (row & 3)) * 8];
    }
#pragma unroll
    for (int mf = 0; mf < 4; ++mf)
#pragma unroll
      for (int nf = 0; nf < 4; ++nf)
        acc[mf][nf] = __builtin_amdgcn_mfma_f32_16x16x32_f16(
            a[mf], b[nf], acc[mf][nf], 0, 0, 0);
  };

  // prologue (R9 correctness-proven ordering)
  loadA(0);
  stageB(0, 0);
  asm volatile("s_waitcnt vmcnt(2)" ::: "memory");  // A(0) regs ready
  writeA(0);
  loadA(32);
  stageB(1, 32);
#pragma unroll
  for (int t = 0; t < NT; ++t) {
    if (t + 1 < NT)
      asm volatile("s_waitcnt vmcnt(6)" ::: "memory");  // Bts[t] complete
    else
      asm volatile("s_waitcnt vmcnt(0)" ::: "memory");
    asm volatile("s_waitcnt lgkmcnt(0)" ::: "memory");  // prev writeA drained
    __builtin_amdgcn_s_barrier();
    if (t + 1 < NT) writeA((t + 1) % 3);  // reg-dep waits handled by compiler
    compute(t % 3);
    if (t + 2 < NT) {
      loadA((t + 2) * 32);
      stageB((t + 2) % 3, (t + 2) * 32);
    }
  }

#pragma unroll
  for (int mf = 0; mf < 4; ++mf) {
#pragma unroll
    for (int nf = 0; nf < 4; ++nf) {
      int col = n0 + wn * 64 + nf * 16 + r16;
      float bs = bias[col];
#pragma unroll
      for (int r = 0; r < 4; ++r) {
        int rowi = m0 + wm * 64 + mf * 16 + g4 * 4 + r;
        QKV[(size_t)z * M_ROWS * D_MODEL + (size_t)rowi * D_MODEL + col] =
            (_Float16)(acc[mf][nf][r] + bs);
      }
    }
  }
}

// ================================================================ K2: attn
// R6/R9 attention body + prologue: blocks u<256 transpose one 32x32 tile of
// wo into woT (f16). Visibility to K3 via the kernel boundary.
// keys j=0..127 map to t = t0-32+j; window for query ql: j in [ql, ql+64].
// OOB keys are zero (score 0 in softmax denom = reference zero-pad).
__global__ __launch_bounds__(256) void k_attn(
    const _Float16* __restrict__ Q, const _Float16* __restrict__ K,
    const _Float16* __restrict__ V, const float* __restrict__ wo,
    _Float16* __restrict__ woT, _Float16* __restrict__ att) {
  __shared__ __align__(16) char smraw[51200];
  const int t0 = blockIdx.x * 64;
  const int h = blockIdx.y;
  const int b = blockIdx.z;
  const int tid = threadIdx.x;
  const int u = blockIdx.x + 32 * blockIdx.y + 256 * blockIdx.z;
  if (u < 256) {
    // transpose one 32x32 tile of wo
    float(*t)[33] = (float(*)[33])smraw;
    int r0 = (u >> 4) * 32, c0 = (u & 15) * 32;
#pragma unroll
    for (int pp = 0; pp < 4; ++pp) {
      int e = pp * 256 + tid;
      t[e >> 5][e & 31] = wo[(size_t)(r0 + (e >> 5)) * D_MODEL + c0 + (e & 31)];
    }
    __syncthreads();
#pragma unroll
    for (int pp = 0; pp < 4; ++pp) {
      int e = pp * 256 + tid;
      woT[(size_t)(c0 + (e >> 5)) * D_MODEL + r0 + (e & 31)] =
          (_Float16)t[e & 31][e >> 5];
    }
    __syncthreads();
  }
  _Float16* Ks = (_Float16*)smraw;                     // 128*64
  _Float16* Vt = (_Float16*)(smraw + 16384);           // 64*136
  _Float16* Ps = (_Float16*)(smraw + 16384 + 17408);   // 64*136
  const int k0 = t0 - 32;
  const int l = tid & 63;
  const int wv = tid >> 6;
  const int r16 = l & 15, g4 = l >> 4;
  const size_t colbase = (size_t)h * HD;
  // Q fragments straight to registers
  f16x8 qf[2];
#pragma unroll
  for (int kk = 0; kk < 2; ++kk)
    qf[kk] = *(const f16x8*)&Q[(size_t)(b * T_SEQ + t0 + wv * 16 + r16) *
                                   D_MODEL + colbase + kk * 32 + g4 * 8];
  // stage K: interior DMA (pre-swizzled source), edge reg path
  const bool interior = (k0 >= 0) && (k0 + 128 <= T_SEQ);
  if (interior) {
#pragma unroll
    for (int cc = 0; cc < 4; ++cc) {
      int c = tid + cc * 256;
      int row = c >> 3, part = c & 7;
      int sp = part ^ (row & 7);
      GLOAD_LDS16(
          &K[(size_t)(b * T_SEQ + k0 + row) * D_MODEL + colbase + sp * 8],
          &Ks[(c - l) * 8]);
    }
  } else {
#pragma unroll
    for (int cc = 0; cc < 4; ++cc) {
      int c = tid + cc * 256;
      int row = c >> 3, part = c & 7;
      int t = k0 + row;
      f16x8 v = {};
      if (t >= 0 && t < T_SEQ)
        v = *(const f16x8*)&K[(size_t)(b * T_SEQ + t) * D_MODEL + colbase +
                              part * 8];
      *(f16x8*)&Ks[row * 64 + (part ^ (row & 7)) * 8] = v;
    }
  }
  // stage V transposed: Vt[dd][key], padded stride 136
#pragma unroll
  for (int cc = 0; cc < 4; ++cc) {
    int c = tid + cc * 256;
    int row = c >> 3, part = c & 7;
    int t = k0 + row;
    f16x8 v = {};
    if (t >= 0 && t < T_SEQ)
      v = *(const f16x8*)&V[(size_t)(b * T_SEQ + t) * D_MODEL + colbase +
                            part * 8];
#pragma unroll
    for (int j = 0; j < 8; ++j) Vt[(part * 8 + j) * 136 + row] = v[j];
  }
  __syncthreads();
  // S = Q K^T : wave wv owns query rows [wv*16, wv*16+16), all 128 keys
  f32x4 s[8] = {};
#pragma unroll
  for (int kk = 0; kk < 2; ++kk) {
    int pp = kk * 4 + g4;
#pragma unroll
    for (int nf = 0; nf < 8; ++nf) {
      f16x8 bb =
          *(const f16x8*)&Ks[(nf * 16 + r16) * 64 + (pp ^ (r16 & 7)) * 8];
      s[nf] =
          __builtin_amdgcn_mfma_f32_16x16x32_f16(qf[kk], bb, s[nf], 0, 0, 0);
    }
  }
  // softmax: lane's rows ql = wv*16 + g4*4 + r ; cols j = nf*16 + r16
#pragma unroll
  for (int r = 0; r < 4; ++r) {
    int ql = wv * 16 + g4 * 4 + r;
    float vals[8];
    float m = -1e30f;
#pragma unroll
    for (int nf = 0; nf < 8; ++nf) {
      int j = nf * 16 + r16;
      bool in = (j >= ql) && (j <= ql + 64);
      float sv = in ? s[nf][r] * 0.125f : -1e30f;
      vals[nf] = sv;
      m = fmaxf(m, sv);
    }
#pragma unroll
    for (int off = 1; off < 16; off <<= 1) m = fmaxf(m, __shfl_xor(m, off, 64));
    float e[8];
    float sum = 0.f;
#pragma unroll
    for (int nf = 0; nf < 8; ++nf) {
      float ev = (vals[nf] > -1e29f) ? __expf(vals[nf] - m) : 0.f;
      e[nf] = ev;
      sum += ev;
    }
#pragma unroll
    for (int off = 1; off < 16; off <<= 1) sum += __shfl_xor(sum, off, 64);
    float inv = 1.f / sum;
#pragma unroll
    for (int nf = 0; nf < 8; ++nf)
      Ps[ql * 136 + nf * 16 + r16] = (_Float16)(e[nf] * inv);
  }
  __syncthreads();
  // O = P V
  f32x4 o[4] = {};
#pragma unroll
  for (int kk = 0; kk < 4; ++kk) {
    f16x8 a = *(const f16x8*)&Ps[(wv * 16 + r16) * 136 + kk * 32 + g4 * 8];
#pragma unroll
    for (int nf = 0; nf < 4; ++nf) {
      f16x8 bb = *(const f16x8*)&Vt[(nf * 16 + r16) * 136 + kk * 32 + g4 * 8];
      o[nf] = __builtin_amdgcn_mfma_f32_16x16x32_f16(a, bb, o[nf], 0, 0, 0);
    }
  }
#pragma unroll
  for (int nf = 0; nf < 4; ++nf)
#pragma unroll
    for (int r = 0; r < 4; ++r) {
      int row = t0 + wv * 16 + g4 * 4 + r;
      int col = nf * 16 + r16;
      att[(size_t)(b * T_SEQ + row) * D_MODEL + colbase + col] =
          (_Float16)o[nf][r];
    }
}

// ================================================================ K3: out
// C = att @ woT^T + bo, fp32 out. BM=64, BN=128, 3-buf counted pipeline,
// T2 swizzle. grid (4,64) = 256 blocks.
template <int OUT_F32, int BM, int BN, int WR>
__device__ __forceinline__ void gemm_phase(
    char* smraw, const _Float16* __restrict__ A,
    const _Float16* __restrict__ Bt, const float* __restrict__ bias,
    void* __restrict__ outBase, int m0, int n0, int tid) {
  constexpr int WC = 4 / WR;
  constexpr int MF = BM / WR / 16;
  constexpr int NF = BN / WC / 16;
  constexpr int NT = D_MODEL / 32;
  constexpr int LPS = BM / 64 + BN / 64;
  _Float16* At = (_Float16*)smraw;
  _Float16* Bts = (_Float16*)(smraw + 3 * BM * 32 * 2);
  const int l = tid & 63;
  const int wv = tid >> 6;
  const int wm = wv / WC, wn = wv % WC;
  const int r16 = l & 15, g4 = l >> 4;
  f32x4 acc[MF][NF] = {};

  auto stage = [&](int bb, int k0) {
#pragma unroll
    for (int cc = 0; cc < BM / 64; ++cc) {
      int c = tid + cc * 256;
      int row = c >> 2, sp = (c & 3) ^ (row & 3);
      GLOAD_LDS16(&A[(size_t)(m0 + row) * D_MODEL + k0 + sp * 8],
                  &At[bb * BM * 32 + (c - l) * 8]);
    }
#pragma unroll
    for (int cc = 0; cc < BN / 64; ++cc) {
      int c = tid + cc * 256;
      int row = c >> 2, sp = (c & 3) ^ (row & 3);
      GLOAD_LDS16(&Bt[(size_t)(n0 + row) * D_MODEL + k0 + sp * 8],
                  &Bts[bb * BN * 32 + (c - l) * 8]);
    }
  };
  auto compute = [&](int bb) {
    f16x8 a[MF], b[NF];
#pragma unroll
    for (int mf = 0; mf < MF; ++mf) {
      int row = wm * (BM / WR) + mf * 16 + r16;
      a[mf] =
          *(const f16x8*)&At[bb * BM * 32 + row * 32 + (g4 ^ (row & 3)) * 8];
    }
#pragma unroll
    for (int nf = 0; nf < NF; ++nf) {
      int row = wn * (BN / WC) + nf * 16 + r16;
      b[nf] =
          *(const f16x8*)&Bts[bb * BN * 32 + row * 32 + (g4 ^ (row & 3)) * 8];
    }
#pragma unroll
    for (int mf = 0; mf < MF; ++mf)
#pragma unroll
      for (int nf = 0; nf < NF; ++nf)
        acc[mf][nf] = __builtin_amdgcn_mfma_f32_16x16x32_f16(
            a[mf], b[nf], acc[mf][nf], 0, 0, 0);
  };

  stage(0, 0);
  stage(1, 32);
#pragma unroll
  for (int t = 0; t < NT; ++t) {
    if (t + 1 < NT)
      asm volatile("s_waitcnt vmcnt(%0)" ::"n"(LPS) : "memory");
    else
      asm volatile("s_waitcnt vmcnt(0)" ::: "memory");
    __builtin_amdgcn_s_barrier();
    compute(t % 3);
    if (t + 2 < NT) stage((t + 2) % 3, (t + 2) * 32);
  }

#pragma unroll
  for (int mf = 0; mf < MF; ++mf) {
#pragma unroll
    for (int nf = 0; nf < NF; ++nf) {
      int col = n0 + wn * (BN / WC) + nf * 16 + r16;
      float bs = bias[col];
#pragma unroll
      for (int r = 0; r < 4; ++r) {
        int rowi = m0 + wm * (BM / WR) + mf * 16 + g4 * 4 + r;
        float v = acc[mf][nf][r] + bs;
        if (OUT_F32)
          ((float*)outBase)[(size_t)rowi * D_MODEL + col] = v;
        else
          ((_Float16*)outBase)[(size_t)rowi * D_MODEL + col] = (_Float16)v;
      }
    }
  }
}

__global__ __launch_bounds__(256) void k_out(
    const _Float16* __restrict__ att, const _Float16* __restrict__ woT,
    const float* __restrict__ bo, float* __restrict__ out) {
  __shared__ __align__(16) char sm[36864];
  gemm_phase<1, 64, 128, 1>(sm, att, woT, bo, out, blockIdx.y * 64,
                            blockIdx.x * 128, threadIdx.x);
}

// ---------------------------------------------------------------- launch
extern "C" void kernel_launch(void* const* d_in, const int* in_sizes, int n_in,
                              void* d_out, int out_size, void* d_ws,
                              size_t ws_size, hipStream_t stream) {
  const float* x = (const float*)d_in[0];
  const float* wq = (const float*)d_in[1];
  const float* bq = (const float*)d_in[2];
  const float* wk = (const float*)d_in[3];
  const float* bk = (const float*)d_in[4];
  const float* wv = (const float*)d_in[5];
  const float* bv = (const float*)d_in[6];
  const float* wo = (const float*)d_in[7];
  const float* bo = (const float*)d_in[8];
  float* out = (float*)d_out;

  char* ws = (char*)d_ws;
  _Float16* wT = (_Float16*)(ws);                    // 1.5 MB (q,k,v panels)
  _Float16* woT = (_Float16*)(ws + (2 << 20));       // 512 KB
  _Float16* QKV = (_Float16*)(ws + (4 << 20));       // 12 MB
  _Float16* att = (_Float16*)(ws + (16 << 20));      // 4 MB
  int* flags = (int*)(ws + (20 << 20));              // 12 ints

  hipMemsetAsync(flags, 0, 64, stream);
  k_qkvw<<<dim3(4, 32, 3), 256, 0, stream>>>(x, wq, wk, wv, bq, bk, bv, wT,
                                             QKV, flags);
  const _Float16* Qm = QKV;
  const _Float16* Km = QKV + (size_t)M_ROWS * D_MODEL;
  const _Float16* Vm = Km + (size_t)M_ROWS * D_MODEL;
  k_attn<<<dim3(32, 8, 2), 256, 0, stream>>>(Qm, Km, Vm, wo, woT, att);
  k_out<<<dim3(4, 64), 256, 0, stream>>>(att, woT, bo, out);
}

// Round 13
// 44.485 us; speedup vs baseline: 1.6182x; 1.6182x over previous
//
#include <hip/hip_runtime.h>

using f16x8 = __attribute__((ext_vector_type(8))) _Float16;
using f16x4 = __attribute__((ext_vector_type(4))) _Float16;
using f32x4 = __attribute__((ext_vector_type(4))) float;

#define T_SEQ 2048
#define D_MODEL 512
#define NH 8
#define HD 64
#define NB 2
#define M_ROWS (NB * T_SEQ)   // 4096

// async global->LDS, 16B per lane. LDS dest must be wave-uniform base;
// HW adds lane*16. Source is per-lane.
#define GLOAD_LDS16(g, l)                                              \
  __builtin_amdgcn_global_load_lds(                                    \
      (const __attribute__((address_space(1))) void*)(g),              \
      (__attribute__((address_space(3))) void*)(l), 16, 0, 0)

// ---------------------------------------------------------------- converts
// fused: blocks [0,2048) convert x -> fp16; blocks [2048,3072) transpose-
// convert the 4 weight matrices and copy qkv biases.
__global__ __launch_bounds__(256) void cvt_all(
    const float* __restrict__ x, const float* __restrict__ wq,
    const float* __restrict__ wk, const float* __restrict__ wv,
    const float* __restrict__ wo, const float* __restrict__ bq,
    const float* __restrict__ bk, const float* __restrict__ bv,
    _Float16* __restrict__ xh, _Float16* __restrict__ wT,
    float* __restrict__ bias3) {
  int bid = blockIdx.x;
  int i = threadIdx.x;
  if (bid < 2048) {
    int idx = (bid * 256 + i) * 4;
    float4 v = *(const float4*)(x + idx);
    f16x4 h;
    h[0] = (_Float16)v.x; h[1] = (_Float16)v.y;
    h[2] = (_Float16)v.z; h[3] = (_Float16)v.w;
    *(f16x4*)(xh + idx) = h;
    return;
  }
  bid -= 2048;
  const int z = bid >> 8;
  const int by = (bid >> 4) & 15;
  const int bx = bid & 15;
  const float* w = z == 0 ? wq : z == 1 ? wk : z == 2 ? wv : wo;
  __shared__ float t[32][33];
  int r0 = by * 32, c0 = bx * 32;
#pragma unroll
  for (int p = 0; p < 4; ++p) {
    int e = p * 256 + i;
    t[e >> 5][e & 31] = w[(size_t)(r0 + (e >> 5)) * D_MODEL + c0 + (e & 31)];
  }
  __syncthreads();
  _Float16* o = wT + (size_t)z * D_MODEL * D_MODEL;
#pragma unroll
  for (int p = 0; p < 4; ++p) {
    int e = p * 256 + i;
    o[(size_t)(c0 + (e >> 5)) * D_MODEL + r0 + (e & 31)] =
        (_Float16)t[e & 31][e >> 5];
  }
  if (bx == 0 && by == 0 && z < 3) {
    const float* bb = z == 0 ? bq : z == 1 ? bk : bv;
#pragma unroll
    for (int p = 0; p < 2; ++p)
      bias3[z * D_MODEL + p * 256 + i] = bb[p * 256 + i];
  }
}

// ---------------------------------------------------------------- GEMM phase
// C[m][n] = sum_k A[m][k] * Bt[n][k] + bias[n]
// 3-buffer 2-deep prefetch, counted vmcnt (T3+T4); LDS XOR-swizzle via
// pre-swizzled global source + swizzled reads (T2 both-sides involution).
template <int OUT_F32, int BM, int BN, int WR>
__device__ __forceinline__ void gemm_phase(
    char* smraw, const _Float16* __restrict__ A,
    const _Float16* __restrict__ Bt, const float* __restrict__ bias,
    void* __restrict__ outBase, int m0, int n0, int tid) {
  constexpr int WC = 4 / WR;
  constexpr int MF = BM / WR / 16;
  constexpr int NF = BN / WC / 16;
  constexpr int NT = D_MODEL / 32;            // 16 K-steps
  constexpr int LPS = BM / 64 + BN / 64;      // gload_lds per thread/stage
  _Float16* At = (_Float16*)smraw;
  _Float16* Bts = (_Float16*)(smraw + 3 * BM * 32 * 2);
  const int l = tid & 63;
  const int wv = tid >> 6;
  const int wm = wv / WC, wn = wv % WC;
  const int r16 = l & 15, g4 = l >> 4;
  f32x4 acc[MF][NF] = {};

  auto stage = [&](int bb, int k0) {
#pragma unroll
    for (int cc = 0; cc < BM / 64; ++cc) {
      int c = tid + cc * 256;
      int row = c >> 2, sp = (c & 3) ^ (row & 3);
      GLOAD_LDS16(&A[(size_t)(m0 + row) * D_MODEL + k0 + sp * 8],
                  &At[bb * BM * 32 + (c - l) * 8]);
    }
#pragma unroll
    for (int cc = 0; cc < BN / 64; ++cc) {
      int c = tid + cc * 256;
      int row = c >> 2, sp = (c & 3) ^ (row & 3);
      GLOAD_LDS16(&Bt[(size_t)(n0 + row) * D_MODEL + k0 + sp * 8],
                  &Bts[bb * BN * 32 + (c - l) * 8]);
    }
  };
  auto compute = [&](int bb) {
    f16x8 a[MF], b[NF];
#pragma unroll
    for (int mf = 0; mf < MF; ++mf) {
      int row = wm * (BM / WR) + mf * 16 + r16;
      a[mf] =
          *(const f16x8*)&At[bb * BM * 32 + row * 32 + (g4 ^ (row & 3)) * 8];
    }
#pragma unroll
    for (int nf = 0; nf < NF; ++nf) {
      int row = wn * (BN / WC) + nf * 16 + r16;
      b[nf] =
          *(const f16x8*)&Bts[bb * BN * 32 + row * 32 + (g4 ^ (row & 3)) * 8];
    }
#pragma unroll
    for (int mf = 0; mf < MF; ++mf)
#pragma unroll
      for (int nf = 0; nf < NF; ++nf)
        acc[mf][nf] = __builtin_amdgcn_mfma_f32_16x16x32_f16(
            a[mf], b[nf], acc[mf][nf], 0, 0, 0);
  };

  stage(0, 0);
  stage(1, 32);
#pragma unroll
  for (int t = 0; t < NT; ++t) {
    if (t + 1 < NT)
      asm volatile("s_waitcnt vmcnt(%0)" ::"n"(LPS) : "memory");
    else
      asm volatile("s_waitcnt vmcnt(0)" ::: "memory");
    __builtin_amdgcn_s_barrier();
    compute(t % 3);
    if (t + 2 < NT) stage((t + 2) % 3, (t + 2) * 32);
  }

#pragma unroll
  for (int mf = 0; mf < MF; ++mf) {
#pragma unroll
    for (int nf = 0; nf < NF; ++nf) {
      int col = n0 + wn * (BN / WC) + nf * 16 + r16;
      float bs = bias[col];
#pragma unroll
      for (int r = 0; r < 4; ++r) {
        int rowi = m0 + wm * (BM / WR) + mf * 16 + g4 * 4 + r;
        float v = acc[mf][nf][r] + bs;
        if (OUT_F32)
          ((float*)outBase)[(size_t)rowi * D_MODEL + col] = v;
        else
          ((_Float16*)outBase)[(size_t)rowi * D_MODEL + col] = (_Float16)v;
      }
    }
  }
}

// QKV GEMM: BM=128, BN=64 -> 768 blocks = 3/CU exact. XCD-aware swizzle
// (bijective: 768 % 8 == 0): block lin runs on XCD lin%8; remap so each XCD
// owns 96 CONTIGUOUS work units = 12 complete A-panels (all nx,z variants of
// an m0 land on one XCD -> A-tile re-reads are XCD-local L2 hits).
__global__ __launch_bounds__(256) void k_gemm_qkv(
    const _Float16* __restrict__ A, const _Float16* __restrict__ BtBase,
    const float* __restrict__ biasBase, _Float16* __restrict__ outBase) {
  __shared__ __align__(16) char sm[36864];
  int lin = blockIdx.x + 8 * blockIdx.y + 256 * blockIdx.z;  // [0,768)
  int swz = (lin & 7) * 96 + (lin >> 3);                     // bijective
  int z = swz >> 8;            // 256 units per z
  int rem = swz & 255;
  int ny = rem >> 3, nx = rem & 7;
  gemm_phase<0, 128, 64, 2>(
      sm, A, BtBase + (size_t)z * D_MODEL * D_MODEL, biasBase + z * D_MODEL,
      outBase + (size_t)z * M_ROWS * D_MODEL, ny * 128, nx * 64, threadIdx.x);
}

// out GEMM: BM=64, BN=128 -> grid (4,64) = 256 blocks = 1/CU exact.
__global__ __launch_bounds__(256) void k_out(
    const _Float16* __restrict__ att, const _Float16* __restrict__ woT,
    const float* __restrict__ bo, float* __restrict__ out) {
  __shared__ __align__(16) char sm[36864];
  gemm_phase<1, 64, 128, 1>(sm, att, woT, bo, out, blockIdx.y * 64,
                            blockIdx.x * 128, threadIdx.x);
}

// ---------------------------------------------------------------- attention
// one block per (b, h, 64-query tile). keys j=0..127 map to t = t0-32+j.
// window for query ql: j in [ql, ql+64]. out-of-sequence keys are zero
// (score 0 participates in softmax denom = reference zero-pad semantics).
// Q in registers; K XOR-swizzled via pre-swizzled source; Vt/Ps padded 136.
__global__ __launch_bounds__(256) void k_attn(
    const _Float16* __restrict__ Q, const _Float16* __restrict__ K,
    const _Float16* __restrict__ V, _Float16* __restrict__ att) {
  const int t0 = blockIdx.x * 64;
  const int h = blockIdx.y;
  const int b = blockIdx.z;
  const int k0 = t0 - 32;
  __shared__ _Float16 Ks[128 * 64];
  __shared__ _Float16 Vt[64 * 136];
  __shared__ _Float16 Ps[64 * 136];
  const int tid = threadIdx.x;
  const int l = tid & 63;
  const int wv = tid >> 6;
  const int r16 = l & 15, g4 = l >> 4;
  const size_t colbase = (size_t)h * HD;
  // Q fragments straight to registers
  f16x8 qf[2];
#pragma unroll
  for (int kk = 0; kk < 2; ++kk)
    qf[kk] = *(const f16x8*)&Q[(size_t)(b * T_SEQ + t0 + wv * 16 + r16) *
                                   D_MODEL + colbase + kk * 32 + g4 * 8];
  // stage K (128 rows): interior DMA (swizzled source), edge reg path
  const bool interior = (k0 >= 0) && (k0 + 128 <= T_SEQ);
  if (interior) {
#pragma unroll
    for (int cc = 0; cc < 4; ++cc) {
      int c = tid + cc * 256;
      int row = c >> 3, part = c & 7;
      int sp = part ^ (row & 7);
      GLOAD_LDS16(
          &K[(size_t)(b * T_SEQ + k0 + row) * D_MODEL + colbase + sp * 8],
          &Ks[(c - l) * 8]);
    }
  } else {
#pragma unroll
    for (int cc = 0; cc < 4; ++cc) {
      int c = tid + cc * 256;
      int row = c >> 3, part = c & 7;
      int t = k0 + row;
      f16x8 v = {};
      if (t >= 0 && t < T_SEQ)
        v = *(const f16x8*)&K[(size_t)(b * T_SEQ + t) * D_MODEL + colbase +
                              part * 8];
      *(f16x8*)&Ks[row * 64 + (part ^ (row & 7)) * 8] = v;
    }
  }
  // stage V transposed: Vt[dd][key], padded stride 136
#pragma unroll
  for (int cc = 0; cc < 4; ++cc) {
    int c = tid + cc * 256;
    int row = c >> 3, part = c & 7;
    int t = k0 + row;
    f16x8 v = {};
    if (t >= 0 && t < T_SEQ)
      v = *(const f16x8*)&V[(size_t)(b * T_SEQ + t) * D_MODEL + colbase +
                            part * 8];
#pragma unroll
    for (int j = 0; j < 8; ++j) Vt[(part * 8 + j) * 136 + row] = v[j];
  }
  __syncthreads();
  // S = Q K^T : wave wv owns query rows [wv*16, wv*16+16), all 128 keys
  f32x4 s[8] = {};
#pragma unroll
  for (int kk = 0; kk < 2; ++kk) {
    int p = kk * 4 + g4;
#pragma unroll
    for (int nf = 0; nf < 8; ++nf) {
      f16x8 bb =
          *(const f16x8*)&Ks[(nf * 16 + r16) * 64 + (p ^ (r16 & 7)) * 8];
      s[nf] =
          __builtin_amdgcn_mfma_f32_16x16x32_f16(qf[kk], bb, s[nf], 0, 0, 0);
    }
  }
  // softmax: lane's rows ql = wv*16 + g4*4 + r ; cols j = nf*16 + r16
#pragma unroll
  for (int r = 0; r < 4; ++r) {
    int ql = wv * 16 + g4 * 4 + r;
    float vals[8];
    float m = -1e30f;
#pragma unroll
    for (int nf = 0; nf < 8; ++nf) {
      int j = nf * 16 + r16;
      bool in = (j >= ql) && (j <= ql + 64);
      float sv = in ? s[nf][r] * 0.125f : -1e30f;
      vals[nf] = sv;
      m = fmaxf(m, sv);
    }
#pragma unroll
    for (int off = 1; off < 16; off <<= 1) m = fmaxf(m, __shfl_xor(m, off, 64));
    float e[8];
    float sum = 0.f;
#pragma unroll
    for (int nf = 0; nf < 8; ++nf) {
      float ev = (vals[nf] > -1e29f) ? __expf(vals[nf] - m) : 0.f;
      e[nf] = ev;
      sum += ev;
    }
#pragma unroll
    for (int off = 1; off < 16; off <<= 1) sum += __shfl_xor(sum, off, 64);
    float inv = 1.f / sum;
#pragma unroll
    for (int nf = 0; nf < 8; ++nf)
      Ps[ql * 136 + nf * 16 + r16] = (_Float16)(e[nf] * inv);
  }
  __syncthreads();
  // O = P V : wave wv owns query rows [wv*16, wv*16+16), dims 0..63
  f32x4 o[4] = {};
#pragma unroll
  for (int kk = 0; kk < 4; ++kk) {
    f16x8 a = *(const f16x8*)&Ps[(wv * 16 + r16) * 136 + kk * 32 + g4 * 8];
#pragma unroll
    for (int nf = 0; nf < 4; ++nf) {
      f16x8 bb = *(const f16x8*)&Vt[(nf * 16 + r16) * 136 + kk * 32 + g4 * 8];
      o[nf] = __builtin_amdgcn_mfma_f32_16x16x32_f16(a, bb, o[nf], 0, 0, 0);
    }
  }
#pragma unroll
  for (int nf = 0; nf < 4; ++nf)
#pragma unroll
    for (int r = 0; r < 4; ++r) {
      int row = t0 + wv * 16 + g4 * 4 + r;
      int col = nf * 16 + r16;
      att[(size_t)(b * T_SEQ + row) * D_MODEL + colbase + col] =
          (_Float16)o[nf][r];
    }
}

// ---------------------------------------------------------------- launch
extern "C" void kernel_launch(void* const* d_in, const int* in_sizes, int n_in,
                              void* d_out, int out_size, void* d_ws,
                              size_t ws_size, hipStream_t stream) {
  const float* x = (const float*)d_in[0];
  const float* wq = (const float*)d_in[1];
  const float* bq = (const float*)d_in[2];
  const float* wk = (const float*)d_in[3];
  const float* bk = (const float*)d_in[4];
  const float* wv = (const float*)d_in[5];
  const float* bv = (const float*)d_in[6];
  const float* wo = (const float*)d_in[7];
  const float* bo = (const float*)d_in[8];
  float* out = (float*)d_out;

  char* ws = (char*)d_ws;
  _Float16* xh = (_Float16*)(ws);                    // 4 MB (reused as att)
  _Float16* wT = (_Float16*)(ws + (4 << 20));        // 2 MB
  float* bias3 = (float*)(ws + (6 << 20));           // 6 KB
  _Float16* QKV = (_Float16*)(ws + (6 << 20) + (64 << 10));  // 12 MB
  _Float16* att = xh;                                // reuse x-half region

  cvt_all<<<3072, 256, 0, stream>>>(x, wq, wk, wv, wo, bq, bk, bv, xh, wT,
                                    bias3);
  k_gemm_qkv<<<dim3(8, 32, 3), 256, 0, stream>>>(xh, wT, bias3, QKV);
  const _Float16* Qm = QKV;
  const _Float16* Km = QKV + (size_t)M_ROWS * D_MODEL;
  const _Float16* Vm = Km + (size_t)M_ROWS * D_MODEL;
  k_attn<<<dim3(32, 8, 2), 256, 0, stream>>>(Qm, Km, Vm, att);
  k_out<<<dim3(4, 64), 256, 0, stream>>>(
      att, wT + (size_t)3 * D_MODEL * D_MODEL, bo, out);
}